// Round 15
// baseline (434.613 us; speedup 1.0000x reference)
//
#include <hip/hip_runtime.h>
#include <hip/hip_bf16.h>
#include <math.h>

// ---- model constants ----
#define B_SZ    8
#define SEQ     4096
#define DMODEL  256
#define DIN     512     // d_inner
#define DSTATE  64
#define NH      8
#define HD      64
#define CONVDIM 640
#define DPROJ   1160
#define NPAD    1280    // DPROJ padded to 10*128
#define NCHUNK  32      // scan chunks per (b,h)
#define CLEN    128     // SEQ / NCHUNK
#define STR64   68      // LDS row stride (shorts) for K=64 tiles
#define STR128  132     // LDS row stride (shorts) for K=128 tiles

typedef unsigned long long u64;
typedef unsigned int u32;
typedef unsigned short u16;
typedef __attribute__((ext_vector_type(8))) short bf16x8;
typedef __attribute__((ext_vector_type(4))) float f32x4;

__device__ __forceinline__ float siluf(float v){ return v / (1.f + __expf(-v)); }   // native v_exp
__device__ __forceinline__ u16 f2bf(float f){ __hip_bfloat16 h = __float2bfloat16(f); return *(u16*)&h; }
__device__ __forceinline__ float bf2f(u16 u){ union{u32 i; float f;} t; t.i = ((u32)u)<<16; return t.f; }
__device__ __forceinline__ bf16x8 ldfrag(const u16* base){
  union { u64 u[2]; bf16x8 v; } t;
  const u64* p = (const u64*)base;
  t.u[0] = p[0]; t.u[1] = p[1];
  return t.v;
}
// async global->LDS DMA, 16 B per lane; dst must be the wave-uniform base
__device__ __forceinline__ void gload16(const u16* g, u16* l){
  __builtin_amdgcn_global_load_lds((const __attribute__((address_space(1))) void*)g,
                                   (__attribute__((address_space(3))) void*)l, 16, 0, 0);
}
// counted waits + barrier WITH compiler memory fence (bare builtin s_barrier is not a fence)
#define WAIT_VM(N)   asm volatile("s_waitcnt vmcnt(" #N ")" ::: "memory")
#define BARF()       asm volatile("s_barrier" ::: "memory")

// ---------------- weight conversion (once per launch) ----------------
__global__ __launch_bounds__(256) void cvt_inw(const float* __restrict__ W, u16* __restrict__ Wt)
{
  const int blk = blockIdx.x;
  const int l = blk / NPAD, n = blk % NPAD;
  const int k = threadIdx.x;
  float v = 0.f;
  if (n < DPROJ) v = W[((long)l*DMODEL + k)*DPROJ + n];
  Wt[((long)l*NPAD + n)*DMODEL + k] = f2bf(v);
}

__global__ __launch_bounds__(256) void cvt_outw(const float* __restrict__ W, u16* __restrict__ Wt)
{
  const int blk = blockIdx.x;
  const int l = blk / DMODEL, n = blk % DMODEL;
  #pragma unroll
  for (int q = 0; q < 2; ++q) {
    const int k = threadIdx.x + q*256;
    const float v = W[((long)l*DIN + k)*DMODEL + n];
    Wt[((long)l*DMODEL + n)*DIN + k] = f2bf(v);
  }
}

// ---------------- encoder GEMM; writes hb bf16 ----------------
__global__ __launch_bounds__(256) void enc_kernel(const float* __restrict__ x,
    const float* __restrict__ W, const float* __restrict__ bias, u16* __restrict__ hb)
{
  __shared__ float xl[32*64];
  const int tid = threadIdx.x;
  const long t0 = (long)blockIdx.x * 32;
  for (int i = tid; i < 32*64; i += 256) xl[i] = x[t0*64 + i];
  __syncthreads();
  float acc[32];
  const float bv = bias[tid];
  #pragma unroll
  for (int tok = 0; tok < 32; ++tok) acc[tok] = bv;
  for (int k = 0; k < 64; ++k) {
    const float wv = W[k*DMODEL + tid];
    #pragma unroll
    for (int tok = 0; tok < 32; ++tok) acc[tok] += xl[tok*64 + k] * wv;
  }
  #pragma unroll
  for (int tok = 0; tok < 32; ++tok)
    hb[(t0 + tok)*DMODEL + tid] = f2bf(acc[tok]);
}

// ---------------- in_proj MFMA GEMM (R2 schedule, z-tiles DROPPED): 128x128 tile, BK=64 ring-2,
// counted vmcnt(8), transposed-MFMA epilogue. Grid (Mb/128, 6): n0 = 512 + by*128 (xbc + dt only).
__global__ __launch_bounds__(256) void inproj_mfma(const u16* __restrict__ hb,
    const u16* __restrict__ Wt, u16* __restrict__ xbc,
    float* __restrict__ dtb, float* __restrict__ lab,
    const float* __restrict__ dt_bias, const float* __restrict__ A_log)
{
  __shared__ __align__(16) u16 Asl[2][128*64];   // 2 x 16 KB
  __shared__ __align__(16) u16 Bsl[2][128*64];   // 2 x 16 KB   (total 64 KB)
  const int tid = threadIdx.x;
  const long m0 = (long)blockIdx.x * 128;
  const int nt = blockIdx.y;            // 0..5
  const int n0 = DIN + nt * 128;        // global col base (512..1152)
  const int w = tid >> 6, lane = tid & 63;
  const int q = lane >> 4, l16 = lane & 15;
  const int wr = (w >> 1) * 64;   // wave row base (0/64)
  const int wc = (w & 1) * 64;    // wave col base (0/64)
  const int wbase = tid & 192;    // wave-uniform thread base
  const int crow = tid >> 3, e0 = (tid & 7) ^ (crow & 7);

  #define STAGE_A(sel, k0) { \
    _Pragma("unroll") \
    for (int i = 0; i < 4; ++i) \
      gload16(hb + (m0 + i*32 + crow)*DMODEL + (k0) + e0*8, &Asl[sel][(i*256 + wbase)*8]); }
  #define STAGE_B(sel, k0) { \
    _Pragma("unroll") \
    for (int i = 0; i < 4; ++i) \
      gload16(Wt + (long)(n0 + i*32 + crow)*DMODEL + (k0) + e0*8, &Bsl[sel][(i*256 + wbase)*8]); }

  STAGE_A(0, 0)  STAGE_B(0, 0)      // 8 loads/wave
  STAGE_A(1, 64) STAGE_B(1, 64)     // 8 more: 16 outstanding

  f32x4 acc[4][4] = {};
  #pragma unroll
  for (int k = 0; k < 4; ++k) {
    const int sel = k & 1;
    if (k < 3) { WAIT_VM(8); }      // current k-step landed; next 8 stay in flight
    else       { WAIT_VM(0); }      // last step: only its own loads outstanding
    BARF();                         // all waves' chunks visible
    #pragma unroll
    for (int ks = 0; ks < 2; ++ks) {
      bf16x8 af[4], bfr[4];
      const int e = ks*4 + q;
      #pragma unroll
      for (int mi = 0; mi < 4; ++mi) {
        const int row = wr + mi*16 + l16;
        af[mi] = ldfrag(&Asl[sel][row*64 + ((e ^ (row & 7))*8)]);
      }
      #pragma unroll
      for (int nj = 0; nj < 4; ++nj) {
        const int row = wc + nj*16 + l16;
        bfr[nj] = ldfrag(&Bsl[sel][row*64 + ((e ^ (row & 7))*8)]);
      }
      #pragma unroll
      for (int nj = 0; nj < 4; ++nj) {
        if (nt == 5 && nj > 0) continue;   // dt tile: only cols 1152..1167 matter
        #pragma unroll
        for (int mi = 0; mi < 4; ++mi)
          acc[mi][nj] = __builtin_amdgcn_mfma_f32_16x16x32_bf16(bfr[nj], af[mi], acc[mi][nj], 0, 0, 0);
      }
    }
    if (k < 2) {                    // prefetch k+2 into the buffer just consumed
      BARF();                       // everyone done reading buf[sel]
      STAGE_A(sel, (k+2)*64)  STAGE_B(sel, (k+2)*64)
    }
  }

  // ---- epilogue: transposed acc -> direct packed stores ----
  // acc[mi][nj][r] = out[token = m0+wr+mi*16+l16][col = n0+wc+nj*16+q*4+r]
  if (nt < 5) {
    u16* const base = xbc + (n0 - DIN);
    #pragma unroll
    for (int mi = 0; mi < 4; ++mi) {
      const long row = m0 + wr + mi*16 + l16;
      #pragma unroll
      for (int nj = 0; nj < 4; ++nj) {
        const int col = wc + nj*16 + q*4;
        const u64 pk = (u64)f2bf(acc[mi][nj][0]) | ((u64)f2bf(acc[mi][nj][1]) << 16)
                     | ((u64)f2bf(acc[mi][nj][2]) << 32) | ((u64)f2bf(acc[mi][nj][3]) << 48);
        *(u64*)(base + row*CONVDIM + col) = pk;
      }
    }
  } else if (wc == 0 && q < 2) {
    // dt tile: global cols 1152..1159 = local 0..7 -> nj==0, q<2, waves with wc==0
    #pragma unroll
    for (int mi = 0; mi < 4; ++mi) {
      const long row = m0 + wr + mi*16 + l16;
      #pragma unroll
      for (int r = 0; r < 4; ++r) {
        const int hh = q*4 + r;
        const float dv = acc[mi][0][r] + dt_bias[hh];
        const float sp = dv > 20.f ? dv : log1pf(expf(dv));
        dtb[row*NH + hh] = sp;
        lab[row*NH + hh] = sp * (-expf(A_log[hh]));   // log dA
      }
    }
  }
  #undef STAGE_A
  #undef STAGE_B
}

// ---------------- out_proj fused v9: Hs LDS ELIMINATED ----------------
// After v8's hoist, Hs served only (a) the one-time hfr load and (b) scalar residual reads
// (the remaining 2.4M bank conflicts: 4 rows x same col set -> 4-way on ds_read_u16).
// Both now come from global: the staging swizzle cancels for hfr
// (Hs[zrow][(e^s)*8] == hb[m0+zrow][e*8]), and the residual is a thread-local
// read(loop1)->write(loop2) of the same hb element (no hazard). -64 KB LDS, -2048 DMA chunks,
// zero scalar LDS reads. Everything else identical to v8 (R14-measured, 44.6us).
__global__ __launch_bounds__(512) void outproj_fused(const u16* __restrict__ yb,
    const u16* __restrict__ Wz, const u16* __restrict__ Wo, u16* __restrict__ hb,
    const float* __restrict__ nw, const float* __restrict__ lnw, const float* __restrict__ lnb)
{
  __shared__ __align__(16) u16 Wzs[2][32*256];  // 2 x 16 KB, Wz chunk double buffer (swz)
  __shared__ __align__(16) u16 Bsl[256*64];     // 32 KB, Wout 2-iter rows (swz)
  __shared__ __align__(16) u16 Zs[128*64];      // 16 KB, g*nw chunk (3-bit slot swz)
  __shared__ float nwl[512];
  __shared__ float rscaleL[128];
  __shared__ float red[128][2][2];              // [row][colgroup][sum, sumsq] for LN
  const int tid = threadIdx.x;                  // 512
  const long m0 = (long)blockIdx.x * 128;
  const int w = tid >> 6, lane = tid & 63;
  const int q = lane >> 4, l16 = lane & 15;
  const int wr = (w >> 1) * 32;                 // GEMM#2 wave row base (0/32/64/96)
  const int wc = (w & 1) * 128;                 // GEMM#2 wave col base (0/128)
  const int zrow = w*16 + l16;                  // z-phase token row (0..127)
  const int wbase = tid & 448;                  // wave-uniform thread base (512 thr)

  // ---- prologue: async-DMA Wzs[0] + Bsl{iters 0,1} ----
  #pragma unroll
  for (int i = 0; i < 2; ++i) {
    const int id = i*512 + tid;
    const int row = id >> 5, p = id & 31;
    gload16(Wz + (long)row*DMODEL + ((p ^ (row & 7))*8), Wzs[0] + (i*512 + wbase)*8);
  }
  #pragma unroll
  for (int i = 0; i < 4; ++i) {                // 2048 chunks: 256 rows x 8 chunks (64 k-cols)
    const int id = i*512 + tid;
    const int row = id >> 3, p = id & 7;
    gload16(Wo + (long)row*DIN + ((p ^ (row & 7))*8), Bsl + (i*512 + wbase)*8);
  }
  nwl[tid] = nw[tid];

  // iteration-invariant hb fragments for the z-phase, straight from global (L2-hot)
  const u16* const hbrow = hb + (m0 + zrow)*DMODEL;
  bf16x8 hfr[8];
  #pragma unroll
  for (int ks = 0; ks < 8; ++ks)
    hfr[ks] = ldfrag(hbrow + (ks*4 + q)*8);

  WAIT_VM(0); BARF();

  float sq = 0.f;
  f32x4 acc[2][8] = {{{0.f,0.f,0.f,0.f}}};
  #pragma unroll 1
  for (int kk = 0; kk < 16; ++kk) {
    const int buf = kk & 1;
    const int k0 = kk*32;
    // stage Bsl for {kk, kk+1} at even iters (readers of prev content done at prior end-barrier)
    if (kk > 0 && (kk & 1) == 0) {
      #pragma unroll
      for (int i = 0; i < 4; ++i) {
        const int id = i*512 + tid;
        const int row = id >> 3, p = id & 7;
        gload16(Wo + (long)row*DIN + k0 + ((p ^ (row & 7))*8), Bsl + (i*512 + wbase)*8);
      }
    }
    // issue next iter's Wzs into the other buffer (readers finished 2 barriers ago)
    if (kk < 15) {
      const int k0n = k0 + 32;
      #pragma unroll
      for (int i = 0; i < 2; ++i) {
        const int id = i*512 + tid;
        const int row = id >> 5, p = id & 31;
        gload16(Wz + (long)(k0n + row)*DMODEL + ((p ^ (row & 7))*8), Wzs[buf^1] + (i*512 + wbase)*8);
      }
    }
    // ---- z-MFMA: wave w owns tokens w*16..+15. Transposed: lane token=l16, col=q*4+r ----
    {
      f32x4 zacc[2] = {};
      #pragma unroll
      for (int ks = 0; ks < 8; ++ks) {
        const int e = ks*4 + q;
        #pragma unroll
        for (int nj = 0; nj < 2; ++nj) {
          const int wrow = nj*16 + l16;
          const bf16x8 wf = ldfrag(&Wzs[buf][wrow*256 + ((e ^ (wrow & 7))*8)]);
          zacc[nj] = __builtin_amdgcn_mfma_f32_16x16x32_bf16(wf, hfr[ks], zacc[nj], 0, 0, 0);
        }
      }
      #pragma unroll
      for (int nj = 0; nj < 2; ++nj) {
        const int col0 = k0 + nj*16 + q*4;        // global z-col (0..511)
        const u64 yv = *(const u64*)(yb + (m0 + zrow)*DIN + col0);
        u64 pk = 0;
        #pragma unroll
        for (int j = 0; j < 4; ++j) {
          const float yf = bf2f((u16)(yv >> (16*j)));
          const float g = yf * siluf(zacc[nj][j]);
          sq += g*g;
          pk |= ((u64)f2bf(g * nwl[col0 + j])) << (16*j);
        }
        const int g4 = nj*4 + q;                  // 4-short group within 32 cols
        const int cchk = g4 >> 1;                 // data chunk 0..3
        const int slot = cchk ^ (zrow & 7);       // 3-bit XOR slot 0..7
        *(u64*)(Zs + zrow*64 + slot*8 + (g4 & 1)*4) = pk;
      }
    }
    WAIT_VM(0);        // Bsl (if staged) + Wzs[kk+1] landed (z-phase cover)
    BARF();            // B_A: Zs + Bsl visible to all waves
    // ---- GEMM#2 (R2-verified orientation): out[row=wr+mi*16+q*4+r][col=wc+nj*16+l16] ----
    {
      bf16x8 af[2], bfr[8];
      #pragma unroll
      for (int mi=0;mi<2;mi++){
        const int row = wr + mi*16 + l16;
        af[mi] = ldfrag(&Zs[row*64 + ((q ^ (row & 7))*8)]);
      }
      const int e2 = (kk & 1)*4 + q;             // k-chunk within the 2-iter Bsl row
      #pragma unroll
      for (int nj=0;nj<8;nj++){
        const int row = wc + nj*16 + l16;
        bfr[nj] = ldfrag(&Bsl[row*64 + ((e2 ^ (row & 7))*8)]);
      }
      #pragma unroll
      for (int mi=0;mi<2;mi++)
        #pragma unroll
        for (int nj=0;nj<8;nj++)
          acc[mi][nj] = __builtin_amdgcn_mfma_f32_16x16x32_bf16(af[mi], bfr[nj], acc[mi][nj], 0,0,0);
    }
    BARF();            // end: reads done; next iter may overwrite Zs (and Bsl at even iters)
  }
  // RMS scale: lane's sq covers 1/4 of its token's cols; reduce over q-lanes (xor 16, 32)
  sq += __shfl_xor(sq, 16);
  sq += __shfl_xor(sq, 32);
  if (lane < 16) rscaleL[w*16 + lane] = rsqrtf(sq*(1.f/512.f) + 1e-5f);
  __syncthreads();
  // o = acc*rms_scale + resid(hb, global; thread-local read-then-write) ; LN stats via shuffle+LDS
  #pragma unroll
  for (int mi=0;mi<2;mi++){
    #pragma unroll
    for (int r=0;r<4;r++){
      const int lrow = wr + mi*16 + q*4 + r;
      const float rscale = rscaleL[lrow];
      float s = 0.f, ss = 0.f;
      #pragma unroll
      for (int nj=0;nj<8;nj++){
        const int col = wc + nj*16 + l16;
        const float hv = bf2f(hb[(m0+lrow)*DMODEL + col]);
        const float o = acc[mi][nj][r]*rscale + hv;
        acc[mi][nj][r] = o;
        s += o; ss += o*o;
      }
      #pragma unroll
      for (int o2=1;o2<16;o2<<=1){ s += __shfl_xor(s,o2); ss += __shfl_xor(ss,o2); }
      if (l16 == 0) { red[lrow][w&1][0] = s; red[lrow][w&1][1] = ss; }
    }
  }
  __syncthreads();
  #pragma unroll
  for (int mi=0;mi<2;mi++){
    #pragma unroll
    for (int r=0;r<4;r++){
      const int lrow = wr + mi*16 + q*4 + r;
      const float S  = red[lrow][0][0] + red[lrow][1][0];
      const float SS = red[lrow][0][1] + red[lrow][1][1];
      const float mu = S * (1.f/256.f);
      const float var = SS * (1.f/256.f) - mu*mu;
      const float rs = rsqrtf(var + 1e-5f);
      #pragma unroll
      for (int nj=0;nj<8;nj++){
        const int col = wc + nj*16 + l16;
        const float v = (acc[mi][nj][r] - mu)*rs*lnw[col] + lnb[col];
        hb[(m0+lrow)*DMODEL + col] = f2bf(v);
      }
    }
  }
}

// ---------------- depthwise causal conv + SiLU: strip kernel ----------------
__global__ __launch_bounds__(256) void conv_kernel(const u16* __restrict__ xbc,
    const float* __restrict__ cw, const float* __restrict__ cb,
    u16* __restrict__ xsx, u16* __restrict__ Bb, u16* __restrict__ Cb)
{
  const long idx = (long)blockIdx.x * 256 + threadIdx.x;   // Mb*20 threads
  const int c4 = (int)(idx % 160) * 4;
  const long bt0 = (idx / 160) * 8;          // strip start (strips never cross batch)
  const int tseq = (int)(bt0 & (SEQ-1));
  const float4 b4 = *(const float4*)(cb + c4);
  const float4 w0v = *(const float4*)(cw + (c4+0)*4);
  const float4 w1v = *(const float4*)(cw + (c4+1)*4);
  const float4 w2v = *(const float4*)(cw + (c4+2)*4);
  const float4 w3v = *(const float4*)(cw + (c4+3)*4);
  const float W0[4] = {w0v.x,w0v.y,w0v.z,w0v.w};
  const float W1[4] = {w1v.x,w1v.y,w1v.z,w1v.w};
  const float W2[4] = {w2v.x,w2v.y,w2v.z,w2v.w};
  const float W3[4] = {w3v.x,w3v.y,w3v.z,w3v.w};
  float i0[11], i1[11], i2[11], i3[11];
  #pragma unroll
  for (int k = 0; k < 11; ++k) {
    u64 v = 0;
    if (tseq - 3 + k >= 0) v = *(const u64*)(xbc + (bt0 - 3 + k)*CONVDIM + c4);
    i0[k]=bf2f((u16)v); i1[k]=bf2f((u16)(v>>16)); i2[k]=bf2f((u16)(v>>32)); i3[k]=bf2f((u16)(v>>48));
  }
  u16* dst; long base; int stride;
  if (c4 < DIN)              { dst = xsx; base = bt0*DIN + c4;              stride = DIN; }
  else if (c4 < DIN+DSTATE)  { dst = Bb;  base = bt0*DSTATE + (c4-DIN);     stride = DSTATE; }
  else                       { dst = Cb;  base = bt0*DSTATE + (c4-DIN-DSTATE); stride = DSTATE; }
  #pragma unroll
  for (int j = 0; j < 8; ++j) {
    float a0=b4.x, a1=b4.y, a2=b4.z, a3=b4.w;
    #pragma unroll
    for (int k = 0; k < 4; ++k) {
      a0 += W0[k]*i0[j+k]; a1 += W1[k]*i1[j+k];
      a2 += W2[k]*i2[j+k]; a3 += W3[k]*i3[j+k];
    }
    a0=siluf(a0); a1=siluf(a1); a2=siluf(a2); a3=siluf(a3);
    const u64 r = (u64)f2bf(a0) | ((u64)f2bf(a1)<<16) | ((u64)f2bf(a2)<<32) | ((u64)f2bf(a3)<<48);
    *(u64*)(dst + base + (long)j*stride) = r;
  }
}

// ---------------- SSD phase A: per chunk-head local state via MFMA; Sloc bf16 ----------------
// Staging vectorized: u64 global loads (4 consecutive n per lane), transpose via 4 unpack writes.
__global__ __launch_bounds__(256) void scanS_kernel(const u16* __restrict__ xsx,
    const u16* __restrict__ Bb, const float* __restrict__ lab, const float* __restrict__ dtb,
    u16* __restrict__ Sloc, float* __restrict__ Pb)
{
  __shared__ __align__(16) u16 Btr[64*STR128];   // [n][s]
  __shared__ __align__(16) u16 Uw[64*STR128];    // [p][s]
  __shared__ float cexpL[128];
  const int wg = blockIdx.x;
  const int c = wg & (NCHUNK-1), bh = wg >> 5, hh = bh & (NH-1), b = bh >> 3;
  const int tid = threadIdx.x;
  const long bt0 = (long)b*SEQ + c*CLEN;
  if (tid < 64) {   // wave 0: inclusive prefix of log dA over 128 steps
    float a0 = lab[(bt0+tid)*NH + hh];
    float a1 = lab[(bt0+64+tid)*NH + hh];
    const float d0 = dtb[(bt0+tid)*NH + hh];
    const float d1 = dtb[(bt0+64+tid)*NH + hh];
    #pragma unroll
    for (int o=1;o<64;o<<=1){
      const float t0=__shfl_up(a0,o), t1=__shfl_up(a1,o);
      if (tid>=o){a0+=t0;a1+=t1;}
    }
    a1 += __shfl(a0,63);
    const float ctot = __shfl(a1,63);
    cexpL[tid]    = d0*__expf(ctot - a0);
    cexpL[tid+64] = d1*__expf(ctot - a1);
    if (tid==0) Pb[wg] = __expf(ctot);
  }
  __syncthreads();
  {
    const int srow = tid >> 4;      // 0..15
    const int seg  = tid & 15;      // 0..15 -> 4 consecutive n
    #pragma unroll
    for (int it = 0; it < 8; ++it) {
      const int s = it*16 + srow;
      const long gr = bt0 + s;
      const u64 bv = *(const u64*)(Bb  + gr*DSTATE + seg*4);
      const u64 xv = *(const u64*)(xsx + gr*DIN + hh*HD + seg*4);
      const float ce = cexpL[s];
      #pragma unroll
      for (int j = 0; j < 4; ++j) {
        const int n = seg*4 + j;
        Btr[n*STR128 + s] = (u16)(bv >> (16*j));
        Uw[n*STR128 + s]  = f2bf(ce * bf2f((u16)(xv >> (16*j))));
      }
    }
  }
  __syncthreads();
  const int w = tid>>6, lane = tid&63, q = lane>>4, l16 = lane&15;
  f32x4 acc[4] = {};
  #pragma unroll
  for (int ks=0;ks<4;ks++){
    const bf16x8 af = ldfrag(&Uw[(w*16+l16)*STR128 + ks*32 + q*8]);
    #pragma unroll
    for (int nj=0;nj<4;nj++){
      const bf16x8 bf = ldfrag(&Btr[(nj*16+l16)*STR128 + ks*32 + q*8]);
      acc[nj] = __builtin_amdgcn_mfma_f32_16x16x32_bf16(af, bf, acc[nj], 0,0,0);
    }
  }
  const long sb = (long)wg*4096;   // [wg][p][n] bf16
  #pragma unroll
  for (int nj=0;nj<4;nj++)
    #pragma unroll
    for (int r=0;r<4;r++)
      Sloc[sb + (w*16+q*4+r)*64 + nj*16 + l16] = f2bf(acc[nj][r]);
}

// Parallel combine over bf16 Sloc: run stays fp32 in registers; u64 vectorized.
// v3 (R13): 4-deep load-ahead pipeline, fully unrolled (static vb indices, rule #20).
__global__ __launch_bounds__(64) void scanMid_kernel(u16* __restrict__ Sloc, const float* __restrict__ Pb)
{
  const int bh = blockIdx.x;
  const int rq = blockIdx.y;            // 0..15
  const int t  = threadIdx.x;           // 0..63
  const long b0 = ((long)bh*NCHUNK)*4096 + rq*256 + t*4;
  float run[4] = {0.f,0.f,0.f,0.f};
  u64 vb[4];
  #pragma unroll
  for (int j = 0; j < 4; ++j) vb[j] = *(const u64*)(Sloc + b0 + (long)j*4096);
  #pragma unroll
  for (int c = 0; c < NCHUNK; ++c) {
    const u64 v = vb[c & 3];
    if (c + 4 < NCHUNK) vb[c & 3] = *(const u64*)(Sloc + b0 + (long)(c+4)*4096);
    const float Pc = Pb[bh*NCHUNK + c];
    u64 o = 0;
    #pragma unroll
    for (int j=0;j<4;j++){
      const float tmp = bf2f((u16)(v >> (16*j)));
      o |= ((u64)f2bf(run[j])) << (16*j);
      run[j] = run[j]*Pc + tmp;
    }
    *(u64*)(Sloc + b0 + (long)c*4096) = o;
  }
}

// ---------------- SSD phase C: Y = ((C Bt) o L) U + diag(exp(cum)) (C h0) + D*x ----------------
// v2 (R12-measured): Bs/Cs/h0t via async gload16 DMA issued at kernel entry (inproj bank
// geometry); Ut register-staged transpose; Ms/y-bounce overlays unchanged.
__global__ __launch_bounds__(512) void scanY_kernel(const u16* __restrict__ xsx,
    u16* __restrict__ yg, const u16* __restrict__ Bb, const u16* __restrict__ Cb,
    const float* __restrict__ lab, const float* __restrict__ dtb,
    const u16* __restrict__ Sinit, const float* __restrict__ Dp)
{
  __shared__ __align__(16) u16 pool[2*128*STR64];  // Bs | Cs (swz, 64-short rows); Ms overlay; y-bounce
  __shared__ __align__(16) u16 Ut[64*STR128];      // [p][s]
  __shared__ __align__(16) u16 h0t[64*64];         // [p][n] (swz, 64-short rows)
  __shared__ float cumL[128];
  __shared__ float dtL[128];
  u16* Bs = pool;                    // [128][64] swz
  u16* Cs = pool + 128*64;           // [128][64] swz
  u16* Ms = pool;                    // overlay after Bs/Cs reads done (needs 16891 <= 17408 ok)

  const int wg = blockIdx.x;
  const int c = wg & (NCHUNK-1), bh = wg >> 5, hh = bh & (NH-1), b = bh >> 3;
  const int tid = threadIdx.x;       // 512
  const long bt0 = (long)b*SEQ + c*CLEN;
  const int wbase = tid & 448;       // wave-uniform base (8 waves)

  // ---- issue all DMA up front (independent of dtL): Bs 1024 + Cs 1024 + h0t 512 chunks ----
  #pragma unroll
  for (int i = 0; i < 2; ++i) {
    const int id = i*512 + tid;
    const int row = id >> 3, p = id & 7;       // row = s 0..127, chunk p 0..7
    gload16(Bb + (bt0 + row)*DSTATE + ((p ^ (row & 7))*8), Bs + (i*512 + wbase)*8);
  }
  #pragma unroll
  for (int i = 0; i < 2; ++i) {
    const int id = i*512 + tid;
    const int row = id >> 3, p = id & 7;
    gload16(Cb + (bt0 + row)*DSTATE + ((p ^ (row & 7))*8), Cs + (i*512 + wbase)*8);
  }
  {
    const int row = tid >> 3, p = tid & 7;     // row = p-dim 0..63, chunk 0..7
    gload16(Sinit + (long)wg*4096 + row*64 + ((p ^ (row & 7))*8), h0t + wbase*8);
  }

  if (tid < 64) {
    float a0 = lab[(bt0+tid)*NH + hh];
    float a1 = lab[(bt0+64+tid)*NH + hh];
    dtL[tid]    = dtb[(bt0+tid)*NH + hh];
    dtL[tid+64] = dtb[(bt0+64+tid)*NH + hh];
    #pragma unroll
    for (int o=1;o<64;o<<=1){
      const float t0=__shfl_up(a0,o), t1=__shfl_up(a1,o);
      if (tid>=o){a0+=t0;a1+=t1;}
    }
    a1 += __shfl(a0,63);
    cumL[tid]=a0; cumL[tid+64]=a1;
  }
  __syncthreads();                   // dtL/cumL ready
  {
    // Ut transpose staging (register path): 4 consecutive n per lane
    const int srow = tid >> 4;      // 0..31
    const int seg  = tid & 15;      // 0..15 -> 4 consecutive n
    #pragma unroll
    for (int it = 0; it < 4; ++it) {
      const int s = it*32 + srow;
      const long gr = bt0 + s;
      const u64 xv = *(const u64*)(xsx + gr*DIN + hh*HD + seg*4);
      const float dts = dtL[s];
      #pragma unroll
      for (int j = 0; j < 4; ++j)
        Ut[(seg*4+j)*STR128 + s] = f2bf(dts * bf2f((u16)(xv >> (16*j))));
    }
  }
  WAIT_VM(0);                        // DMA (Bs/Cs/h0t) landed
  BARF();                            // everything visible

  const int w = tid>>6, lane = tid&63, q = lane>>4, l16 = lane&15;
  f32x4 accG[8] = {};
  f32x4 accI[4] = {};
  #pragma unroll
  for (int ks=0;ks<2;ks++){
    const int rowa = w*16 + l16;
    const int e = ks*4 + q;
    const bf16x8 af = ldfrag(&Cs[rowa*64 + ((e ^ (rowa & 7))*8)]);
    #pragma unroll
    for (int nj=0;nj<8;nj++){
      const int row = nj*16 + l16;
      accG[nj] = __builtin_amdgcn_mfma_f32_16x16x32_bf16(af, ldfrag(&Bs[row*64 + ((e ^ (row & 7))*8)]), accG[nj], 0,0,0);
    }
    #pragma unroll
    for (int nj=0;nj<4;nj++){
      const int row = nj*16 + l16;
      accI[nj] = __builtin_amdgcn_mfma_f32_16x16x32_bf16(af, ldfrag(&h0t[row*64 + ((e ^ (row & 7))*8)]), accI[nj], 0,0,0);
    }
  }
  __syncthreads();
  #pragma unroll
  for (int nj=0;nj<8;nj++){
    const int s = nj*16 + l16;
    #pragma unroll
    for (int r=0;r<4;r++){
      const int t = w*16 + q*4 + r;
      const float v = (s<=t) ? accG[nj][r]*__expf(cumL[t]-cumL[s]) : 0.f;
      Ms[t*STR128 + s] = f2bf(v);
    }
  }
  __syncthreads();
  f32x4 accY[4] = {};
  #pragma unroll
  for (int ks=0;ks<4;ks++){
    const bf16x8 af = ldfrag(&Ms[(w*16+l16)*STR128 + ks*32 + q*8]);
    #pragma unroll
    for (int nj=0;nj<4;nj++)
      accY[nj] = __builtin_amdgcn_mfma_f32_16x16x32_bf16(af, ldfrag(&Ut[(nj*16+l16)*STR128 + ks*32 + q*8]), accY[nj], 0,0,0);
  }
  const float Dv = Dp[hh];
  float rdt[4], ec[4];
  #pragma unroll
  for (int r=0;r<4;r++){
    const int t = w*16 + q*4 + r;
    rdt[r] = 1.f / dtL[t];           // dt = softplus(..) > 0
    ec[r]  = __expf(cumL[t]);
  }
  __syncthreads();   // Ms reads done; reuse pool as y-bounce [128][STR64]
  #pragma unroll
  for (int nj=0;nj<4;nj++){
    const int p = nj*16 + l16;
    #pragma unroll
    for (int r=0;r<4;r++){
      const int t = w*16 + q*4 + r;
      const float xv = bf2f(Ut[p*STR128 + t]) * rdt[r];   // x = (dt*x)/dt
      pool[t*STR64 + p] = f2bf(accY[nj][r] + ec[r]*accI[nj][r] + Dv*xv);
    }
  }
  __syncthreads();
  {
    const int row = tid >> 2, seg = tid & 3;
    const u64* s = (const u64*)(pool + row*STR64 + seg*16);
    u64 a=s[0], b2=s[1], c2=s[2], d=s[3];
    u64* dptr = (u64*)(yg + (bt0+row)*DIN + hh*HD + seg*16);
    dptr[0]=a; dptr[1]=b2; dptr[2]=c2; dptr[3]=d;
  }
}

// ---------------- decoder: hb bf16 in, fp32 out ----------------
__global__ __launch_bounds__(64) void dec_kernel(const u16* __restrict__ hb,
    const float* __restrict__ W, const float* __restrict__ bias, float* __restrict__ out)
{
  const int wg = blockIdx.x;
  const int b = wg / 10, o = wg % 10;
  const int lane = threadIdx.x;
  const u16* r = hb + ((long)b*SEQ + SEQ-1)*DMODEL;
  float s = 0.f;
  #pragma unroll
  for (int q=0;q<4;q++){ const int k = lane + q*64; s += bf2f(r[k])*W[k*10+o]; }
  #pragma unroll
  for (int o2=32;o2;o2>>=1) s += __shfl_down(s, o2);
  if (lane == 0) out[wg] = s + bias[o];
}

extern "C" void kernel_launch(void* const* d_in, const int* in_sizes, int n_in,
                              void* d_out, int out_size, void* d_ws, size_t ws_size,
                              hipStream_t stream) {
  const float* x        = (const float*)d_in[0];
  const float* enc_w    = (const float*)d_in[1];
  const float* enc_b    = (const float*)d_in[2];
  const float* in_proj  = (const float*)d_in[3];
  const float* conv_w   = (const float*)d_in[4];
  const float* conv_b   = (const float*)d_in[5];
  const float* dt_bias  = (const float*)d_in[6];
  const float* A_log    = (const float*)d_in[7];
  const float* Dp       = (const float*)d_in[8];
  const float* norm_w   = (const float*)d_in[9];
  const float* out_proj = (const float*)d_in[10];
  const float* ln_w     = (const float*)d_in[11];
  const float* ln_b     = (const float*)d_in[12];
  const float* dec_w    = (const float*)d_in[13];
  const float* dec_b    = (const float*)d_in[14];
  float* out = (float*)d_out;

  float* ws = (float*)d_ws;
  u16* WtIn  = (u16*)ws;                       // 2*NPAD*256 shorts = 655360
  u16* WtOut = WtIn + (long)2*NPAD*DMODEL;     // 2*256*512 shorts = 262144
  float* gbase = ws + 327680 + 131072;         // = ws + 458752 floats

  // Per-token fp32-equivalents: hb 128 + xbc 320 + xsx 256 + yg 256
  //                             + Bb 32 + Cb 32 + dtb 8 + lab 8 = 1040
  int NB = 8;
  while (NB > 1) {
    const long Mb = (long)NB * SEQ;
    const long bytes = (458752L + Mb * 1040L + 4096) * 4;
    if ((size_t)bytes <= ws_size) break;
    NB >>= 1;
  }
  const long Mb = (long)NB * SEQ;

  u16*   hb   = (u16*)gbase;              // Mb*256 u16 (residual stream, bf16 only)
  u16*   xbc  = hb + Mb*DMODEL;           // Mb*640 u16 ; aliased by Sloc (Mb*256 u16)
  u16*   xsx  = xbc + Mb*CONVDIM;         // Mb*512 u16
  u16*   yg   = xsx + Mb*DIN;             // Mb*512 u16 (y)
  u16*   Bb   = yg + Mb*DIN;              // Mb*64 u16
  u16*   Cb   = Bb + Mb*DSTATE;           // Mb*64 u16
  float* dtb  = (float*)(Cb + Mb*DSTATE); // Mb*8 f
  float* lab  = dtb + Mb*NH;              // Mb*8 f (log dA)
  float* Pb   = lab + Mb*NH;              // <= 2048
  u16*   Sloc = xbc;                      // alias: xbc dead after conv; Mb*256 u16

  cvt_inw <<<dim3(2*NPAD),   dim3(256), 0, stream>>>(in_proj,  WtIn);
  cvt_outw<<<dim3(2*DMODEL), dim3(256), 0, stream>>>(out_proj, WtOut);

  const int ngroups = B_SZ / NB;
  for (int g = 0; g < ngroups; ++g) {
    const float* xg = x + (long)g*NB*SEQ*64;

    enc_kernel<<<dim3((int)(Mb/32)), dim3(256), 0, stream>>>(xg, enc_w, enc_b, hb);

    for (int l = 0; l < 2; ++l) {
      inproj_mfma<<<dim3((int)(Mb/128), 6), dim3(256), 0, stream>>>(
          hb, WtIn + (long)l*NPAD*DMODEL, xbc, dtb, lab,
          dt_bias + l*NH, A_log + l*NH);
      conv_kernel<<<dim3((int)(Mb*20/256)), dim3(256), 0, stream>>>(
          xbc, conv_w + (long)l*CONVDIM*4, conv_b + (long)l*CONVDIM, xsx, Bb, Cb);
      scanS_kernel<<<dim3(NB*8*NCHUNK), dim3(256), 0, stream>>>(xsx, Bb, lab, dtb, Sloc, Pb);
      scanMid_kernel<<<dim3(NB*8, 16), dim3(64), 0, stream>>>(Sloc, Pb);
      scanY_kernel<<<dim3(NB*8*NCHUNK), dim3(512), 0, stream>>>(xsx, yg, Bb, Cb, lab, dtb, Sloc, Dp + l*NH);
      outproj_fused<<<dim3((int)(Mb/128)), dim3(512), 0, stream>>>(
          yg, WtIn + (long)l*NPAD*DMODEL, WtOut + (long)l*DMODEL*DIN, hb,
          norm_w + (long)l*DIN, ln_w + l*DMODEL, ln_b + l*DMODEL);
    }

    dec_kernel<<<dim3(NB*10), dim3(64), 0, stream>>>(hb, dec_w, dec_b, out + (long)g*NB*10);
  }
}

// Round 16
// 424.879 us; speedup vs baseline: 1.0229x; 1.0229x over previous
//
#include <hip/hip_runtime.h>
#include <hip/hip_bf16.h>
#include <math.h>

// ---- model constants ----
#define B_SZ    8
#define SEQ     4096
#define DMODEL  256
#define DIN     512     // d_inner
#define DSTATE  64
#define NH      8
#define HD      64
#define CONVDIM 640
#define DPROJ   1160
#define NPAD    1280    // DPROJ padded to 10*128
#define NCHUNK  32      // scan chunks per (b,h)
#define CLEN    128     // SEQ / NCHUNK
#define STR64   68      // LDS row stride (shorts) for K=64 tiles
#define STR128  132     // LDS row stride (shorts) for K=128 tiles

typedef unsigned long long u64;
typedef unsigned int u32;
typedef unsigned short u16;
typedef __attribute__((ext_vector_type(8))) short bf16x8;
typedef __attribute__((ext_vector_type(4))) float f32x4;

__device__ __forceinline__ float siluf(float v){ return v / (1.f + __expf(-v)); }   // native v_exp
__device__ __forceinline__ u16 f2bf(float f){ __hip_bfloat16 h = __float2bfloat16(f); return *(u16*)&h; }
__device__ __forceinline__ float bf2f(u16 u){ union{u32 i; float f;} t; t.i = ((u32)u)<<16; return t.f; }
__device__ __forceinline__ bf16x8 ldfrag(const u16* base){
  union { u64 u[2]; bf16x8 v; } t;
  const u64* p = (const u64*)base;
  t.u[0] = p[0]; t.u[1] = p[1];
  return t.v;
}
// async global->LDS DMA, 16 B per lane; dst must be the wave-uniform base
__device__ __forceinline__ void gload16(const u16* g, u16* l){
  __builtin_amdgcn_global_load_lds((const __attribute__((address_space(1))) void*)g,
                                   (__attribute__((address_space(3))) void*)l, 16, 0, 0);
}
// counted waits + barrier WITH compiler memory fence (bare builtin s_barrier is not a fence)
#define WAIT_VM(N)   asm volatile("s_waitcnt vmcnt(" #N ")" ::: "memory")
#define BARF()       asm volatile("s_barrier" ::: "memory")

// ---------------- weight conversion (once per launch) ----------------
__global__ __launch_bounds__(256) void cvt_inw(const float* __restrict__ W, u16* __restrict__ Wt)
{
  const int blk = blockIdx.x;
  const int l = blk / NPAD, n = blk % NPAD;
  const int k = threadIdx.x;
  float v = 0.f;
  if (n < DPROJ) v = W[((long)l*DMODEL + k)*DPROJ + n];
  Wt[((long)l*NPAD + n)*DMODEL + k] = f2bf(v);
}

__global__ __launch_bounds__(256) void cvt_outw(const float* __restrict__ W, u16* __restrict__ Wt)
{
  const int blk = blockIdx.x;
  const int l = blk / DMODEL, n = blk % DMODEL;
  #pragma unroll
  for (int q = 0; q < 2; ++q) {
    const int k = threadIdx.x + q*256;
    const float v = W[((long)l*DIN + k)*DMODEL + n];
    Wt[((long)l*DMODEL + n)*DIN + k] = f2bf(v);
  }
}

// ---------------- encoder GEMM; writes hb bf16 ----------------
__global__ __launch_bounds__(256) void enc_kernel(const float* __restrict__ x,
    const float* __restrict__ W, const float* __restrict__ bias, u16* __restrict__ hb)
{
  __shared__ float xl[32*64];
  const int tid = threadIdx.x;
  const long t0 = (long)blockIdx.x * 32;
  for (int i = tid; i < 32*64; i += 256) xl[i] = x[t0*64 + i];
  __syncthreads();
  float acc[32];
  const float bv = bias[tid];
  #pragma unroll
  for (int tok = 0; tok < 32; ++tok) acc[tok] = bv;
  for (int k = 0; k < 64; ++k) {
    const float wv = W[k*DMODEL + tid];
    #pragma unroll
    for (int tok = 0; tok < 32; ++tok) acc[tok] += xl[tok*64 + k] * wv;
  }
  #pragma unroll
  for (int tok = 0; tok < 32; ++tok)
    hb[(t0 + tok)*DMODEL + tid] = f2bf(acc[tok]);
}

// ---------------- in_proj MFMA GEMM (R2 schedule, z-tiles DROPPED): 128x128 tile, BK=64 ring-2,
// counted vmcnt(8), transposed-MFMA epilogue. Grid (Mb/128, 6): n0 = 512 + by*128 (xbc + dt only).
__global__ __launch_bounds__(256) void inproj_mfma(const u16* __restrict__ hb,
    const u16* __restrict__ Wt, u16* __restrict__ xbc,
    float* __restrict__ dtb, float* __restrict__ lab,
    const float* __restrict__ dt_bias, const float* __restrict__ A_log)
{
  __shared__ __align__(16) u16 Asl[2][128*64];   // 2 x 16 KB
  __shared__ __align__(16) u16 Bsl[2][128*64];   // 2 x 16 KB   (total 64 KB)
  const int tid = threadIdx.x;
  const long m0 = (long)blockIdx.x * 128;
  const int nt = blockIdx.y;            // 0..5
  const int n0 = DIN + nt * 128;        // global col base (512..1152)
  const int w = tid >> 6, lane = tid & 63;
  const int q = lane >> 4, l16 = lane & 15;
  const int wr = (w >> 1) * 64;   // wave row base (0/64)
  const int wc = (w & 1) * 64;    // wave col base (0/64)
  const int wbase = tid & 192;    // wave-uniform thread base
  const int crow = tid >> 3, e0 = (tid & 7) ^ (crow & 7);

  #define STAGE_A(sel, k0) { \
    _Pragma("unroll") \
    for (int i = 0; i < 4; ++i) \
      gload16(hb + (m0 + i*32 + crow)*DMODEL + (k0) + e0*8, &Asl[sel][(i*256 + wbase)*8]); }
  #define STAGE_B(sel, k0) { \
    _Pragma("unroll") \
    for (int i = 0; i < 4; ++i) \
      gload16(Wt + (long)(n0 + i*32 + crow)*DMODEL + (k0) + e0*8, &Bsl[sel][(i*256 + wbase)*8]); }

  STAGE_A(0, 0)  STAGE_B(0, 0)      // 8 loads/wave
  STAGE_A(1, 64) STAGE_B(1, 64)     // 8 more: 16 outstanding

  f32x4 acc[4][4] = {};
  #pragma unroll
  for (int k = 0; k < 4; ++k) {
    const int sel = k & 1;
    if (k < 3) { WAIT_VM(8); }      // current k-step landed; next 8 stay in flight
    else       { WAIT_VM(0); }      // last step: only its own loads outstanding
    BARF();                         // all waves' chunks visible
    #pragma unroll
    for (int ks = 0; ks < 2; ++ks) {
      bf16x8 af[4], bfr[4];
      const int e = ks*4 + q;
      #pragma unroll
      for (int mi = 0; mi < 4; ++mi) {
        const int row = wr + mi*16 + l16;
        af[mi] = ldfrag(&Asl[sel][row*64 + ((e ^ (row & 7))*8)]);
      }
      #pragma unroll
      for (int nj = 0; nj < 4; ++nj) {
        const int row = wc + nj*16 + l16;
        bfr[nj] = ldfrag(&Bsl[sel][row*64 + ((e ^ (row & 7))*8)]);
      }
      #pragma unroll
      for (int nj = 0; nj < 4; ++nj) {
        if (nt == 5 && nj > 0) continue;   // dt tile: only cols 1152..1167 matter
        #pragma unroll
        for (int mi = 0; mi < 4; ++mi)
          acc[mi][nj] = __builtin_amdgcn_mfma_f32_16x16x32_bf16(bfr[nj], af[mi], acc[mi][nj], 0, 0, 0);
      }
    }
    if (k < 2) {                    // prefetch k+2 into the buffer just consumed
      BARF();                       // everyone done reading buf[sel]
      STAGE_A(sel, (k+2)*64)  STAGE_B(sel, (k+2)*64)
    }
  }

  // ---- epilogue: transposed acc -> direct packed stores ----
  // acc[mi][nj][r] = out[token = m0+wr+mi*16+l16][col = n0+wc+nj*16+q*4+r]
  if (nt < 5) {
    u16* const base = xbc + (n0 - DIN);
    #pragma unroll
    for (int mi = 0; mi < 4; ++mi) {
      const long row = m0 + wr + mi*16 + l16;
      #pragma unroll
      for (int nj = 0; nj < 4; ++nj) {
        const int col = wc + nj*16 + q*4;
        const u64 pk = (u64)f2bf(acc[mi][nj][0]) | ((u64)f2bf(acc[mi][nj][1]) << 16)
                     | ((u64)f2bf(acc[mi][nj][2]) << 32) | ((u64)f2bf(acc[mi][nj][3]) << 48);
        *(u64*)(base + row*CONVDIM + col) = pk;
      }
    }
  } else if (wc == 0 && q < 2) {
    // dt tile: global cols 1152..1159 = local 0..7 -> nj==0, q<2, waves with wc==0
    #pragma unroll
    for (int mi = 0; mi < 4; ++mi) {
      const long row = m0 + wr + mi*16 + l16;
      #pragma unroll
      for (int r = 0; r < 4; ++r) {
        const int hh = q*4 + r;
        const float dv = acc[mi][0][r] + dt_bias[hh];
        const float sp = dv > 20.f ? dv : log1pf(expf(dv));
        dtb[row*NH + hh] = sp;
        lab[row*NH + hh] = sp * (-expf(A_log[hh]));   // log dA
      }
    }
  }
  #undef STAGE_A
  #undef STAGE_B
}

// ---------------- out_proj fused v8 (R14-measured BEST, 44.6us): z-recompute, bank-clean
// Zs/Bsl, iteration-invariant Hs fragments hoisted to registers (hfr[8], +32 VGPR) ----------------
__global__ __launch_bounds__(512) void outproj_fused(const u16* __restrict__ yb,
    const u16* __restrict__ Wz, const u16* __restrict__ Wo, u16* __restrict__ hb,
    const float* __restrict__ nw, const float* __restrict__ lnw, const float* __restrict__ lnb)
{
  __shared__ __align__(16) u16 Hs[128*256];     // 64 KB, hb tile (swz)
  __shared__ __align__(16) u16 Wzs[2][32*256];  // 2 x 16 KB, Wz chunk double buffer (swz)
  __shared__ __align__(16) u16 Bsl[256*64];     // 32 KB, Wout 2-iter rows (swz)
  __shared__ __align__(16) u16 Zs[128*64];      // 16 KB, g*nw chunk (3-bit slot swz)
  __shared__ float nwl[512];
  __shared__ float rscaleL[128];
  __shared__ float red[128][2][2];              // [row][colgroup][sum, sumsq] for LN
  const int tid = threadIdx.x;                  // 512
  const long m0 = (long)blockIdx.x * 128;
  const int w = tid >> 6, lane = tid & 63;
  const int q = lane >> 4, l16 = lane & 15;
  const int wr = (w >> 1) * 32;                 // GEMM#2 wave row base (0/32/64/96)
  const int wc = (w & 1) * 128;                 // GEMM#2 wave col base (0/128)
  const int zrow = w*16 + l16;                  // z-phase token row (0..127)
  const int wbase = tid & 448;                  // wave-uniform thread base (512 thr)

  // ---- prologue: async-DMA Hs (4096 chunks) + Wzs[0] + Bsl{iters 0,1} ----
  #pragma unroll
  for (int i = 0; i < 8; ++i) {
    const int id = i*512 + tid;
    const int row = id >> 5, p = id & 31;
    gload16(hb + (m0 + row)*DMODEL + ((p ^ (row & 7))*8), Hs + (i*512 + wbase)*8);
  }
  #pragma unroll
  for (int i = 0; i < 2; ++i) {
    const int id = i*512 + tid;
    const int row = id >> 5, p = id & 31;
    gload16(Wz + (long)row*DMODEL + ((p ^ (row & 7))*8), Wzs[0] + (i*512 + wbase)*8);
  }
  #pragma unroll
  for (int i = 0; i < 4; ++i) {                // 2048 chunks: 256 rows x 8 chunks (64 k-cols)
    const int id = i*512 + tid;
    const int row = id >> 3, p = id & 7;
    gload16(Wo + (long)row*DIN + ((p ^ (row & 7))*8), Bsl + (i*512 + wbase)*8);
  }
  nwl[tid] = nw[tid];
  WAIT_VM(0); BARF();

  // hoist iteration-invariant Hs fragments (lane's token row) into registers
  bf16x8 hfr[8];
  #pragma unroll
  for (int ks = 0; ks < 8; ++ks) {
    const int e = ks*4 + q;
    hfr[ks] = ldfrag(&Hs[zrow*256 + ((e ^ (zrow & 7))*8)]);
  }

  float sq = 0.f;
  f32x4 acc[2][8] = {{{0.f,0.f,0.f,0.f}}};
  #pragma unroll 1
  for (int kk = 0; kk < 16; ++kk) {
    const int buf = kk & 1;
    const int k0 = kk*32;
    // stage Bsl for {kk, kk+1} at even iters (readers of prev content done at prior end-barrier)
    if (kk > 0 && (kk & 1) == 0) {
      #pragma unroll
      for (int i = 0; i < 4; ++i) {
        const int id = i*512 + tid;
        const int row = id >> 3, p = id & 7;
        gload16(Wo + (long)row*DIN + k0 + ((p ^ (row & 7))*8), Bsl + (i*512 + wbase)*8);
      }
    }
    // issue next iter's Wzs into the other buffer (readers finished 2 barriers ago)
    if (kk < 15) {
      const int k0n = k0 + 32;
      #pragma unroll
      for (int i = 0; i < 2; ++i) {
        const int id = i*512 + tid;
        const int row = id >> 5, p = id & 31;
        gload16(Wz + (long)(k0n + row)*DMODEL + ((p ^ (row & 7))*8), Wzs[buf^1] + (i*512 + wbase)*8);
      }
    }
    // ---- z-MFMA: wave w owns tokens w*16..+15. Transposed: lane token=l16, col=q*4+r ----
    {
      f32x4 zacc[2] = {};
      #pragma unroll
      for (int ks = 0; ks < 8; ++ks) {
        const int e = ks*4 + q;
        #pragma unroll
        for (int nj = 0; nj < 2; ++nj) {
          const int wrow = nj*16 + l16;
          const bf16x8 wf = ldfrag(&Wzs[buf][wrow*256 + ((e ^ (wrow & 7))*8)]);
          zacc[nj] = __builtin_amdgcn_mfma_f32_16x16x32_bf16(wf, hfr[ks], zacc[nj], 0, 0, 0);
        }
      }
      #pragma unroll
      for (int nj = 0; nj < 2; ++nj) {
        const int col0 = k0 + nj*16 + q*4;        // global z-col (0..511)
        const u64 yv = *(const u64*)(yb + (m0 + zrow)*DIN + col0);
        u64 pk = 0;
        #pragma unroll
        for (int j = 0; j < 4; ++j) {
          const float yf = bf2f((u16)(yv >> (16*j)));
          const float g = yf * siluf(zacc[nj][j]);
          sq += g*g;
          pk |= ((u64)f2bf(g * nwl[col0 + j])) << (16*j);
        }
        const int g4 = nj*4 + q;                  // 4-short group within 32 cols
        const int cchk = g4 >> 1;                 // data chunk 0..3
        const int slot = cchk ^ (zrow & 7);       // 3-bit XOR slot 0..7
        *(u64*)(Zs + zrow*64 + slot*8 + (g4 & 1)*4) = pk;
      }
    }
    WAIT_VM(0);        // Bsl (if staged) + Wzs[kk+1] landed (z-phase cover)
    BARF();            // B_A: Zs + Bsl visible to all waves
    // ---- GEMM#2 (R2-verified orientation): out[row=wr+mi*16+q*4+r][col=wc+nj*16+l16] ----
    {
      bf16x8 af[2], bfr[8];
      #pragma unroll
      for (int mi=0;mi<2;mi++){
        const int row = wr + mi*16 + l16;
        af[mi] = ldfrag(&Zs[row*64 + ((q ^ (row & 7))*8)]);
      }
      const int e2 = (kk & 1)*4 + q;             // k-chunk within the 2-iter Bsl row
      #pragma unroll
      for (int nj=0;nj<8;nj++){
        const int row = wc + nj*16 + l16;
        bfr[nj] = ldfrag(&Bsl[row*64 + ((e2 ^ (row & 7))*8)]);
      }
      #pragma unroll
      for (int mi=0;mi<2;mi++)
        #pragma unroll
        for (int nj=0;nj<8;nj++)
          acc[mi][nj] = __builtin_amdgcn_mfma_f32_16x16x32_bf16(af[mi], bfr[nj], acc[mi][nj], 0,0,0);
    }
    BARF();            // end: reads done; next iter may overwrite Zs (and Bsl at even iters)
  }
  // RMS scale: lane's sq covers 1/4 of its token's cols; reduce over q-lanes (xor 16, 32)
  sq += __shfl_xor(sq, 16);
  sq += __shfl_xor(sq, 32);
  if (lane < 16) rscaleL[w*16 + lane] = rsqrtf(sq*(1.f/512.f) + 1e-5f);
  __syncthreads();
  // o = acc*rms_scale + resid(Hs, swizzled) ; per-row LN stats via 16-lane shuffle + LDS combine
  #pragma unroll
  for (int mi=0;mi<2;mi++){
    #pragma unroll
    for (int r=0;r<4;r++){
      const int lrow = wr + mi*16 + q*4 + r;
      const float rscale = rscaleL[lrow];
      float s = 0.f, ss = 0.f;
      #pragma unroll
      for (int nj=0;nj<8;nj++){
        const int col = wc + nj*16 + l16;
        const float hv = bf2f(Hs[lrow*256 + ((col >> 3) ^ (lrow & 7))*8 + (col & 7)]);
        const float o = acc[mi][nj][r]*rscale + hv;
        acc[mi][nj][r] = o;
        s += o; ss += o*o;
      }
      #pragma unroll
      for (int o2=1;o2<16;o2<<=1){ s += __shfl_xor(s,o2); ss += __shfl_xor(ss,o2); }
      if (l16 == 0) { red[lrow][w&1][0] = s; red[lrow][w&1][1] = ss; }
    }
  }
  __syncthreads();
  #pragma unroll
  for (int mi=0;mi<2;mi++){
    #pragma unroll
    for (int r=0;r<4;r++){
      const int lrow = wr + mi*16 + q*4 + r;
      const float S  = red[lrow][0][0] + red[lrow][1][0];
      const float SS = red[lrow][0][1] + red[lrow][1][1];
      const float mu = S * (1.f/256.f);
      const float var = SS * (1.f/256.f) - mu*mu;
      const float rs = rsqrtf(var + 1e-5f);
      #pragma unroll
      for (int nj=0;nj<8;nj++){
        const int col = wc + nj*16 + l16;
        const float v = (acc[mi][nj][r] - mu)*rs*lnw[col] + lnb[col];
        hb[(m0+lrow)*DMODEL + col] = f2bf(v);
      }
    }
  }
}

// ---------------- depthwise causal conv + SiLU: strip kernel ----------------
__global__ __launch_bounds__(256) void conv_kernel(const u16* __restrict__ xbc,
    const float* __restrict__ cw, const float* __restrict__ cb,
    u16* __restrict__ xsx, u16* __restrict__ Bb, u16* __restrict__ Cb)
{
  const long idx = (long)blockIdx.x * 256 + threadIdx.x;   // Mb*20 threads
  const int c4 = (int)(idx % 160) * 4;
  const long bt0 = (idx / 160) * 8;          // strip start (strips never cross batch)
  const int tseq = (int)(bt0 & (SEQ-1));
  const float4 b4 = *(const float4*)(cb + c4);
  const float4 w0v = *(const float4*)(cw + (c4+0)*4);
  const float4 w1v = *(const float4*)(cw + (c4+1)*4);
  const float4 w2v = *(const float4*)(cw + (c4+2)*4);
  const float4 w3v = *(const float4*)(cw + (c4+3)*4);
  const float W0[4] = {w0v.x,w0v.y,w0v.z,w0v.w};
  const float W1[4] = {w1v.x,w1v.y,w1v.z,w1v.w};
  const float W2[4] = {w2v.x,w2v.y,w2v.z,w2v.w};
  const float W3[4] = {w3v.x,w3v.y,w3v.z,w3v.w};
  float i0[11], i1[11], i2[11], i3[11];
  #pragma unroll
  for (int k = 0; k < 11; ++k) {
    u64 v = 0;
    if (tseq - 3 + k >= 0) v = *(const u64*)(xbc + (bt0 - 3 + k)*CONVDIM + c4);
    i0[k]=bf2f((u16)v); i1[k]=bf2f((u16)(v>>16)); i2[k]=bf2f((u16)(v>>32)); i3[k]=bf2f((u16)(v>>48));
  }
  u16* dst; long base; int stride;
  if (c4 < DIN)              { dst = xsx; base = bt0*DIN + c4;              stride = DIN; }
  else if (c4 < DIN+DSTATE)  { dst = Bb;  base = bt0*DSTATE + (c4-DIN);     stride = DSTATE; }
  else                       { dst = Cb;  base = bt0*DSTATE + (c4-DIN-DSTATE); stride = DSTATE; }
  #pragma unroll
  for (int j = 0; j < 8; ++j) {
    float a0=b4.x, a1=b4.y, a2=b4.z, a3=b4.w;
    #pragma unroll
    for (int k = 0; k < 4; ++k) {
      a0 += W0[k]*i0[j+k]; a1 += W1[k]*i1[j+k];
      a2 += W2[k]*i2[j+k]; a3 += W3[k]*i3[j+k];
    }
    a0=siluf(a0); a1=siluf(a1); a2=siluf(a2); a3=siluf(a3);
    const u64 r = (u64)f2bf(a0) | ((u64)f2bf(a1)<<16) | ((u64)f2bf(a2)<<32) | ((u64)f2bf(a3)<<48);
    *(u64*)(dst + base + (long)j*stride) = r;
  }
}

// ---------------- SSD phase A: per chunk-head local state via MFMA; Sloc bf16 ----------------
// Staging vectorized: u64 global loads (4 consecutive n per lane), transpose via 4 unpack writes.
__global__ __launch_bounds__(256) void scanS_kernel(const u16* __restrict__ xsx,
    const u16* __restrict__ Bb, const float* __restrict__ lab, const float* __restrict__ dtb,
    u16* __restrict__ Sloc, float* __restrict__ Pb)
{
  __shared__ __align__(16) u16 Btr[64*STR128];   // [n][s]
  __shared__ __align__(16) u16 Uw[64*STR128];    // [p][s]
  __shared__ float cexpL[128];
  const int wg = blockIdx.x;
  const int c = wg & (NCHUNK-1), bh = wg >> 5, hh = bh & (NH-1), b = bh >> 3;
  const int tid = threadIdx.x;
  const long bt0 = (long)b*SEQ + c*CLEN;
  if (tid < 64) {   // wave 0: inclusive prefix of log dA over 128 steps
    float a0 = lab[(bt0+tid)*NH + hh];
    float a1 = lab[(bt0+64+tid)*NH + hh];
    const float d0 = dtb[(bt0+tid)*NH + hh];
    const float d1 = dtb[(bt0+64+tid)*NH + hh];
    #pragma unroll
    for (int o=1;o<64;o<<=1){
      const float t0=__shfl_up(a0,o), t1=__shfl_up(a1,o);
      if (tid>=o){a0+=t0;a1+=t1;}
    }
    a1 += __shfl(a0,63);
    const float ctot = __shfl(a1,63);
    cexpL[tid]    = d0*__expf(ctot - a0);
    cexpL[tid+64] = d1*__expf(ctot - a1);
    if (tid==0) Pb[wg] = __expf(ctot);
  }
  __syncthreads();
  {
    const int srow = tid >> 4;      // 0..15
    const int seg  = tid & 15;      // 0..15 -> 4 consecutive n
    #pragma unroll
    for (int it = 0; it < 8; ++it) {
      const int s = it*16 + srow;
      const long gr = bt0 + s;
      const u64 bv = *(const u64*)(Bb  + gr*DSTATE + seg*4);
      const u64 xv = *(const u64*)(xsx + gr*DIN + hh*HD + seg*4);
      const float ce = cexpL[s];
      #pragma unroll
      for (int j = 0; j < 4; ++j) {
        const int n = seg*4 + j;
        Btr[n*STR128 + s] = (u16)(bv >> (16*j));
        Uw[n*STR128 + s]  = f2bf(ce * bf2f((u16)(xv >> (16*j))));
      }
    }
  }
  __syncthreads();
  const int w = tid>>6, lane = tid&63, q = lane>>4, l16 = lane&15;
  f32x4 acc[4] = {};
  #pragma unroll
  for (int ks=0;ks<4;ks++){
    const bf16x8 af = ldfrag(&Uw[(w*16+l16)*STR128 + ks*32 + q*8]);
    #pragma unroll
    for (int nj=0;nj<4;nj++){
      const bf16x8 bf = ldfrag(&Btr[(nj*16+l16)*STR128 + ks*32 + q*8]);
      acc[nj] = __builtin_amdgcn_mfma_f32_16x16x32_bf16(af, bf, acc[nj], 0,0,0);
    }
  }
  const long sb = (long)wg*4096;   // [wg][p][n] bf16
  #pragma unroll
  for (int nj=0;nj<4;nj++)
    #pragma unroll
    for (int r=0;r<4;r++)
      Sloc[sb + (w*16+q*4+r)*64 + nj*16 + l16] = f2bf(acc[nj][r]);
}

// Parallel combine over bf16 Sloc: run stays fp32 in registers; u64 vectorized.
// v3 (R13): 4-deep load-ahead pipeline, fully unrolled (static vb indices, rule #20).
__global__ __launch_bounds__(64) void scanMid_kernel(u16* __restrict__ Sloc, const float* __restrict__ Pb)
{
  const int bh = blockIdx.x;
  const int rq = blockIdx.y;            // 0..15
  const int t  = threadIdx.x;           // 0..63
  const long b0 = ((long)bh*NCHUNK)*4096 + rq*256 + t*4;
  float run[4] = {0.f,0.f,0.f,0.f};
  u64 vb[4];
  #pragma unroll
  for (int j = 0; j < 4; ++j) vb[j] = *(const u64*)(Sloc + b0 + (long)j*4096);
  #pragma unroll
  for (int c = 0; c < NCHUNK; ++c) {
    const u64 v = vb[c & 3];
    if (c + 4 < NCHUNK) vb[c & 3] = *(const u64*)(Sloc + b0 + (long)(c+4)*4096);
    const float Pc = Pb[bh*NCHUNK + c];
    u64 o = 0;
    #pragma unroll
    for (int j=0;j<4;j++){
      const float tmp = bf2f((u16)(v >> (16*j)));
      o |= ((u64)f2bf(run[j])) << (16*j);
      run[j] = run[j]*Pc + tmp;
    }
    *(u64*)(Sloc + b0 + (long)c*4096) = o;
  }
}

// ---------------- SSD phase C: Y = ((C Bt) o L) U + diag(exp(cum)) (C h0) + D*x ----------------
// v2 (R12-measured): Bs/Cs/h0t via async gload16 DMA issued at kernel entry (inproj bank
// geometry); Ut register-staged transpose; Ms/y-bounce overlays unchanged.
__global__ __launch_bounds__(512) void scanY_kernel(const u16* __restrict__ xsx,
    u16* __restrict__ yg, const u16* __restrict__ Bb, const u16* __restrict__ Cb,
    const float* __restrict__ lab, const float* __restrict__ dtb,
    const u16* __restrict__ Sinit, const float* __restrict__ Dp)
{
  __shared__ __align__(16) u16 pool[2*128*STR64];  // Bs | Cs (swz, 64-short rows); Ms overlay; y-bounce
  __shared__ __align__(16) u16 Ut[64*STR128];      // [p][s]
  __shared__ __align__(16) u16 h0t[64*64];         // [p][n] (swz, 64-short rows)
  __shared__ float cumL[128];
  __shared__ float dtL[128];
  u16* Bs = pool;                    // [128][64] swz
  u16* Cs = pool + 128*64;           // [128][64] swz
  u16* Ms = pool;                    // overlay after Bs/Cs reads done (needs 16891 <= 17408 ok)

  const int wg = blockIdx.x;
  const int c = wg & (NCHUNK-1), bh = wg >> 5, hh = bh & (NH-1), b = bh >> 3;
  const int tid = threadIdx.x;       // 512
  const long bt0 = (long)b*SEQ + c*CLEN;
  const int wbase = tid & 448;       // wave-uniform base (8 waves)

  // ---- issue all DMA up front (independent of dtL): Bs 1024 + Cs 1024 + h0t 512 chunks ----
  #pragma unroll
  for (int i = 0; i < 2; ++i) {
    const int id = i*512 + tid;
    const int row = id >> 3, p = id & 7;       // row = s 0..127, chunk p 0..7
    gload16(Bb + (bt0 + row)*DSTATE + ((p ^ (row & 7))*8), Bs + (i*512 + wbase)*8);
  }
  #pragma unroll
  for (int i = 0; i < 2; ++i) {
    const int id = i*512 + tid;
    const int row = id >> 3, p = id & 7;
    gload16(Cb + (bt0 + row)*DSTATE + ((p ^ (row & 7))*8), Cs + (i*512 + wbase)*8);
  }
  {
    const int row = tid >> 3, p = tid & 7;     // row = p-dim 0..63, chunk 0..7
    gload16(Sinit + (long)wg*4096 + row*64 + ((p ^ (row & 7))*8), h0t + wbase*8);
  }

  if (tid < 64) {
    float a0 = lab[(bt0+tid)*NH + hh];
    float a1 = lab[(bt0+64+tid)*NH + hh];
    dtL[tid]    = dtb[(bt0+tid)*NH + hh];
    dtL[tid+64] = dtb[(bt0+64+tid)*NH + hh];
    #pragma unroll
    for (int o=1;o<64;o<<=1){
      const float t0=__shfl_up(a0,o), t1=__shfl_up(a1,o);
      if (tid>=o){a0+=t0;a1+=t1;}
    }
    a1 += __shfl(a0,63);
    cumL[tid]=a0; cumL[tid+64]=a1;
  }
  __syncthreads();                   // dtL/cumL ready
  {
    // Ut transpose staging (register path): 4 consecutive n per lane
    const int srow = tid >> 4;      // 0..31
    const int seg  = tid & 15;      // 0..15 -> 4 consecutive n
    #pragma unroll
    for (int it = 0; it < 4; ++it) {
      const int s = it*32 + srow;
      const long gr = bt0 + s;
      const u64 xv = *(const u64*)(xsx + gr*DIN + hh*HD + seg*4);
      const float dts = dtL[s];
      #pragma unroll
      for (int j = 0; j < 4; ++j)
        Ut[(seg*4+j)*STR128 + s] = f2bf(dts * bf2f((u16)(xv >> (16*j))));
    }
  }
  WAIT_VM(0);                        // DMA (Bs/Cs/h0t) landed
  BARF();                            // everything visible

  const int w = tid>>6, lane = tid&63, q = lane>>4, l16 = lane&15;
  f32x4 accG[8] = {};
  f32x4 accI[4] = {};
  #pragma unroll
  for (int ks=0;ks<2;ks++){
    const int rowa = w*16 + l16;
    const int e = ks*4 + q;
    const bf16x8 af = ldfrag(&Cs[rowa*64 + ((e ^ (rowa & 7))*8)]);
    #pragma unroll
    for (int nj=0;nj<8;nj++){
      const int row = nj*16 + l16;
      accG[nj] = __builtin_amdgcn_mfma_f32_16x16x32_bf16(af, ldfrag(&Bs[row*64 + ((e ^ (row & 7))*8)]), accG[nj], 0,0,0);
    }
    #pragma unroll
    for (int nj=0;nj<4;nj++){
      const int row = nj*16 + l16;
      accI[nj] = __builtin_amdgcn_mfma_f32_16x16x32_bf16(af, ldfrag(&h0t[row*64 + ((e ^ (row & 7))*8)]), accI[nj], 0,0,0);
    }
  }
  __syncthreads();
  #pragma unroll
  for (int nj=0;nj<8;nj++){
    const int s = nj*16 + l16;
    #pragma unroll
    for (int r=0;r<4;r++){
      const int t = w*16 + q*4 + r;
      const float v = (s<=t) ? accG[nj][r]*__expf(cumL[t]-cumL[s]) : 0.f;
      Ms[t*STR128 + s] = f2bf(v);
    }
  }
  __syncthreads();
  f32x4 accY[4] = {};
  #pragma unroll
  for (int ks=0;ks<4;ks++){
    const bf16x8 af = ldfrag(&Ms[(w*16+l16)*STR128 + ks*32 + q*8]);
    #pragma unroll
    for (int nj=0;nj<4;nj++)
      accY[nj] = __builtin_amdgcn_mfma_f32_16x16x32_bf16(af, ldfrag(&Ut[(nj*16+l16)*STR128 + ks*32 + q*8]), accY[nj], 0,0,0);
  }
  const float Dv = Dp[hh];
  float rdt[4], ec[4];
  #pragma unroll
  for (int r=0;r<4;r++){
    const int t = w*16 + q*4 + r;
    rdt[r] = 1.f / dtL[t];           // dt = softplus(..) > 0
    ec[r]  = __expf(cumL[t]);
  }
  __syncthreads();   // Ms reads done; reuse pool as y-bounce [128][STR64]
  #pragma unroll
  for (int nj=0;nj<4;nj++){
    const int p = nj*16 + l16;
    #pragma unroll
    for (int r=0;r<4;r++){
      const int t = w*16 + q*4 + r;
      const float xv = bf2f(Ut[p*STR128 + t]) * rdt[r];   // x = (dt*x)/dt
      pool[t*STR64 + p] = f2bf(accY[nj][r] + ec[r]*accI[nj][r] + Dv*xv);
    }
  }
  __syncthreads();
  {
    const int row = tid >> 2, seg = tid & 3;
    const u64* s = (const u64*)(pool + row*STR64 + seg*16);
    u64 a=s[0], b2=s[1], c2=s[2], d=s[3];
    u64* dptr = (u64*)(yg + (bt0+row)*DIN + hh*HD + seg*16);
    dptr[0]=a; dptr[1]=b2; dptr[2]=c2; dptr[3]=d;
  }
}

// ---------------- decoder: hb bf16 in, fp32 out ----------------
__global__ __launch_bounds__(64) void dec_kernel(const u16* __restrict__ hb,
    const float* __restrict__ W, const float* __restrict__ bias, float* __restrict__ out)
{
  const int wg = blockIdx.x;
  const int b = wg / 10, o = wg % 10;
  const int lane = threadIdx.x;
  const u16* r = hb + ((long)b*SEQ + SEQ-1)*DMODEL;
  float s = 0.f;
  #pragma unroll
  for (int q=0;q<4;q++){ const int k = lane + q*64; s += bf2f(r[k])*W[k*10+o]; }
  #pragma unroll
  for (int o2=32;o2;o2>>=1) s += __shfl_down(s, o2);
  if (lane == 0) out[wg] = s + bias[o];
}

extern "C" void kernel_launch(void* const* d_in, const int* in_sizes, int n_in,
                              void* d_out, int out_size, void* d_ws, size_t ws_size,
                              hipStream_t stream) {
  const float* x        = (const float*)d_in[0];
  const float* enc_w    = (const float*)d_in[1];
  const float* enc_b    = (const float*)d_in[2];
  const float* in_proj  = (const float*)d_in[3];
  const float* conv_w   = (const float*)d_in[4];
  const float* conv_b   = (const float*)d_in[5];
  const float* dt_bias  = (const float*)d_in[6];
  const float* A_log    = (const float*)d_in[7];
  const float* Dp       = (const float*)d_in[8];
  const float* norm_w   = (const float*)d_in[9];
  const float* out_proj = (const float*)d_in[10];
  const float* ln_w     = (const float*)d_in[11];
  const float* ln_b     = (const float*)d_in[12];
  const float* dec_w    = (const float*)d_in[13];
  const float* dec_b    = (const float*)d_in[14];
  float* out = (float*)d_out;

  float* ws = (float*)d_ws;
  u16* WtIn  = (u16*)ws;                       // 2*NPAD*256 shorts = 655360
  u16* WtOut = WtIn + (long)2*NPAD*DMODEL;     // 2*256*512 shorts = 262144
  float* gbase = ws + 327680 + 131072;         // = ws + 458752 floats

  // Per-token fp32-equivalents: hb 128 + xbc 320 + xsx 256 + yg 256
  //                             + Bb 32 + Cb 32 + dtb 8 + lab 8 = 1040
  int NB = 8;
  while (NB > 1) {
    const long Mb = (long)NB * SEQ;
    const long bytes = (458752L + Mb * 1040L + 4096) * 4;
    if ((size_t)bytes <= ws_size) break;
    NB >>= 1;
  }
  const long Mb = (long)NB * SEQ;

  u16*   hb   = (u16*)gbase;              // Mb*256 u16 (residual stream, bf16 only)
  u16*   xbc  = hb + Mb*DMODEL;           // Mb*640 u16 ; aliased by Sloc (Mb*256 u16)
  u16*   xsx  = xbc + Mb*CONVDIM;         // Mb*512 u16
  u16*   yg   = xsx + Mb*DIN;             // Mb*512 u16 (y)
  u16*   Bb   = yg + Mb*DIN;              // Mb*64 u16
  u16*   Cb   = Bb + Mb*DSTATE;           // Mb*64 u16
  float* dtb  = (float*)(Cb + Mb*DSTATE); // Mb*8 f
  float* lab  = dtb + Mb*NH;              // Mb*8 f (log dA)
  float* Pb   = lab + Mb*NH;              // <= 2048
  u16*   Sloc = xbc;                      // alias: xbc dead after conv; Mb*256 u16

  cvt_inw <<<dim3(2*NPAD),   dim3(256), 0, stream>>>(in_proj,  WtIn);
  cvt_outw<<<dim3(2*DMODEL), dim3(256), 0, stream>>>(out_proj, WtOut);

  const int ngroups = B_SZ / NB;
  for (int g = 0; g < ngroups; ++g) {
    const float* xg = x + (long)g*NB*SEQ*64;

    enc_kernel<<<dim3((int)(Mb/32)), dim3(256), 0, stream>>>(xg, enc_w, enc_b, hb);

    for (int l = 0; l < 2; ++l) {
      inproj_mfma<<<dim3((int)(Mb/128), 6), dim3(256), 0, stream>>>(
          hb, WtIn + (long)l*NPAD*DMODEL, xbc, dtb, lab,
          dt_bias + l*NH, A_log + l*NH);
      conv_kernel<<<dim3((int)(Mb*20/256)), dim3(256), 0, stream>>>(
          xbc, conv_w + (long)l*CONVDIM*4, conv_b + (long)l*CONVDIM, xsx, Bb, Cb);
      scanS_kernel<<<dim3(NB*8*NCHUNK), dim3(256), 0, stream>>>(xsx, Bb, lab, dtb, Sloc, Pb);
      scanMid_kernel<<<dim3(NB*8, 16), dim3(64), 0, stream>>>(Sloc, Pb);
      scanY_kernel<<<dim3(NB*8*NCHUNK), dim3(512), 0, stream>>>(xsx, yg, Bb, Cb, lab, dtb, Sloc, Dp + l*NH);
      outproj_fused<<<dim3((int)(Mb/128)), dim3(512), 0, stream>>>(
          yg, WtIn + (long)l*NPAD*DMODEL, WtOut + (long)l*DMODEL*DIN, hb,
          norm_w + (long)l*DIN, ln_w + l*DMODEL, ln_b + l*DMODEL);
    }

    dec_kernel<<<dim3(NB*10), dim3(64), 0, stream>>>(hb, dec_w, dec_b, out + (long)g*NB*10);
  }
}